// Round 12
// baseline (183.468 us; speedup 1.0000x reference)
//
#include <hip/hip_runtime.h>

typedef unsigned int   uint_;
typedef unsigned short u16;
typedef _Float16 f16;
typedef __attribute__((ext_vector_type(8))) _Float16 f16x8;  // MFMA A/B frag
typedef __attribute__((ext_vector_type(2))) _Float16 f16x2;
typedef __attribute__((ext_vector_type(2))) __fp16 fp16x2_builtin;
typedef __attribute__((ext_vector_type(4))) float f4;

// Problem constants
#define B_    8
#define CIN_  64
#define H_    128
#define W_    128
#define OC_   128
#define HO_   64
#define WO_   64
#define NPOS  (B_ * HO_ * WO_)   // 32768

// ws layout (float offsets)
#define XBT_OFF  0          // f16 x_bt (B,H,W,64) = 8388608 f16 = 4194304 floats
#define MF_OFF   4194304    // u16[4096]  (f16 M frags)
#define WF_OFF   4196352    // u16[16384] (f16 Wv frags)
#define WPOS_OFF 4204544    // wpos0[25] @ +0, wpos1[25] @ +32 (pre-scaled 2^-8)
#define DUMMY_OFF 6000000   // probe sink: 1024*512 floats

// ---------------------------------------------------------------------------
// helpers
// ---------------------------------------------------------------------------
__device__ __forceinline__ uint_ h2u(f16x2 h) {
  union { uint_ u; f16x2 h; } c; c.h = h; return c.u;
}
__device__ __forceinline__ u16 f2h_bits(float x) {
  union { f16 h; u16 u; } c; c.h = (f16)x; return c.u;
}
__device__ __forceinline__ f16x2 cvt_pk2h(float lo, float hi) {
  union { fp16x2_builtin b; f16x2 h; } c;
  c.b = __builtin_amdgcn_cvt_pkrtz(lo, hi);
  return c.h;
}

template <int CTRL>
__device__ __forceinline__ float dpp_add(float x) {
  int y = __builtin_amdgcn_update_dpp(0, __float_as_int(x), CTRL, 0xf, 0xf, true);
  return x + __int_as_float(y);
}

__device__ __forceinline__ float fdot2h(f16x2 a, f16x2 b, float c) {
#if __has_builtin(__builtin_amdgcn_fdot2)
  return __builtin_amdgcn_fdot2(a, b, c, false);
#else
  return fmaf((float)a[0], (float)b[0], fmaf((float)a[1], (float)b[1], c));
#endif
}

// ---------------------------------------------------------------------------
// Dispatch 1 (mega): unchanged from R11.
// ---------------------------------------------------------------------------
__global__ __launch_bounds__(256) void mega_kernel(
    const float* __restrict__ x, u16* __restrict__ xbt,
    const float* __restrict__ w_q, const float* __restrict__ w_k,
    const float* __restrict__ w_v,
    const float* __restrict__ row_emb, const float* __restrict__ col_emb,
    const float* __restrict__ mix_emb,
    u16* __restrict__ MF, u16* __restrict__ WF, float* __restrict__ wpos) {
  if (blockIdx.x < 1024) {
    __shared__ float tile[64][129];
    int by = blockIdx.x;
    int b = by >> 7, y = by & 127;
    const float* xp = x + (size_t)b * (CIN_ * H_ * W_) + (size_t)y * W_;
    #pragma unroll
    for (int it = 0; it < 32; ++it) {
      int idx = threadIdx.x + it * 256;
      int c = idx >> 7, xw = idx & 127;
      tile[c][xw] = xp[(size_t)c * (H_ * W_) + xw];
    }
    __syncthreads();
    uint_* dst = (uint_*)(xbt + ((size_t)(b * H_ + y)) * (W_ * 64));
    #pragma unroll
    for (int it = 0; it < 16; ++it) {
      int idx = threadIdx.x + it * 256;   // = xw*32 + cp
      int xw = idx >> 5, cp = idx & 31;
      dst[idx] = h2u(cvt_pk2h(tile[2 * cp][xw], tile[2 * cp + 1][xw]));
    }
  } else {
    int pb = blockIdx.x - 1024;   // 0..32
    if (pb < 16) {
      int idx = pb * 256 + threadIdx.x;  // 0..4095
      int a = idx >> 6, c = idx & 63;
      float acc = 0.f;
      #pragma unroll 8
      for (int o = 0; o < 128; ++o)
        acc = fmaf(w_q[o * 64 + a], w_k[o * 64 + c], acc);
      int m = c >> 4, lr = c & 15;
      int ks = a >> 5, q = (a >> 3) & 3, jr = a & 7;
      int off = ((ks * 4 + m) * 64 + (lr + 16 * q)) * 8 + jr;
      MF[off] = f2h_bits(acc);
    } else if (pb == 16) {
      int p = threadIdx.x;
      if (p < 25) {
        int i = p / 5, j = p % 5;
        float a0 = 0.f, a1 = 0.f;
        for (int c = 0; c < 128; ++c) {
          float rc = row_emb[c * 5 + i] + col_emb[c * 5 + j];
          a0 = fmaf(rc, mix_emb[c * 2 + 0], a0);
          a1 = fmaf(rc, mix_emb[c * 2 + 1], a1);
        }
        float mx = fmaxf(a0, a1);
        float e0 = __expf(a0 - mx), e1 = __expf(a1 - mx);
        float inv = 0.00390625f / (e0 + e1);   // softmax * 2^-8
        wpos[p] = e0 * inv;
        wpos[32 + p] = e1 * inv;
      }
    } else {
      int t = (pb - 17) * 256 + threadIdx.x;  // 0..4095
      #pragma unroll
      for (int e = 0; e < 4; ++e) {
        int elem = t * 4 + e;            // = c*128 + k
        int c = elem >> 7, k = elem & 127;
        int m = c >> 4, lr = c & 15;
        int ks = k >> 5, q = (k >> 3) & 3, j = k & 7;
        int off = ((ks * 8 + m) * 64 + (lr + 16 * q)) * 8 + j;
        WF[off] = f2h_bits(w_v[elem]);
      }
    }
  }
}

// ---------------------------------------------------------------------------
// Dispatch 2: real fused kernel, byte-identical to R11.
// ---------------------------------------------------------------------------
__global__ __launch_bounds__(512) void attn_out_kernel(
    const u16* __restrict__ xbt, const u16* __restrict__ MF,
    const float* __restrict__ wpos, const u16* __restrict__ WF,
    float* __restrict__ out) {
  __shared__ u16 Xl[5 * 67 * 68];
  __shared__ union {
    float Ul[32][68];
    u16   Gl[32][136];
  } GU;

  int tid = threadIdx.x;
  int wave = tid >> 6, lane = tid & 63;
  int lr = lane & 15, q = lane >> 4;

  int bid = (int)blockIdx.x;
  int swz = (bid & 7) * 128 + (bid >> 3);
  int pos0 = swz * 32;

  int b = pos0 >> 12;
  int ho0 = (pos0 >> 6) & 63;
  int y0 = 2 * ho0, x0base = 2 * (pos0 & 63);

  {
    int sl = tid & 15;
    int pi0 = tid >> 4;
    const u16* xbb = xbt + (size_t)b * (H_ * W_ * 64);
    #pragma unroll
    for (int it = 0; it < 11; ++it) {
      int pi = it * 32 + pi0;
      if (pi < 335) {
        int row = pi / 67;
        int col = pi - row * 67;
        int yr = y0 + row - 2, xr = x0base + col - 2;
        bool oob = ((unsigned)yr >= (unsigned)H_) | ((unsigned)xr >= (unsigned)W_);
        int yc = min(max(yr, 0), H_ - 1);
        int xc = min(max(xr, 0), W_ - 1);
        uint2 d = *(const uint2*)(xbb + ((size_t)yc * W_ + xc) * 64 + sl * 4);
        if (oob) { d.x = 0u; d.y = 0u; }
        *(uint2*)(&Xl[pi * 68 + sl * 4]) = d;
      }
    }
  }

  {
    int pt = wave >> 2, mm = wave & 3;
    int pu = pos0 + pt * 16 + lr;
    int bu = pu >> 12, hou = (pu >> 6) & 63, wou = pu & 63;
    const u16* xq = xbt + ((size_t)(bu * H_ + 2 * hou) * W_ + 2 * wou) * 64;
    f4 ua = (f4)0.f;
    #pragma unroll
    for (int ks = 0; ks < 2; ++ks) {
      f16x8 bb = *reinterpret_cast<const f16x8*>(xq + ks * 32 + q * 8);
      f16x8 ah = *reinterpret_cast<const f16x8*>(
          MF + ((ks * 4 + mm) * 64 + lane) * 8);
      ua = __builtin_amdgcn_mfma_f32_16x16x32_f16(ah, bb, ua, 0, 0, 0);
    }
    #pragma unroll
    for (int r = 0; r < 4; ++r)
      GU.Ul[pt * 16 + lr][mm * 16 + q * 4 + r] = ua[r];
  }
  __syncthreads();

  {
    int r = wave * 4 + q;
    const u16* xl0 = &Xl[(2 * r) * 68 + lr * 4];

    f4 u = *reinterpret_cast<const f4*>(&GU.Ul[r][lr * 4]);
    f16x2 u01 = cvt_pk2h(u.x, u.y);
    f16x2 u23 = cvt_pk2h(u.z, u.w);

    float Z = 0.f;
    f16x2 g0a = (f16x2)0.f, g0b = (f16x2)0.f;
    f16x2 g1a = (f16x2)0.f, g1b = (f16x2)0.f;

    #pragma unroll
    for (int p = 0; p < 25; ++p) {
      const int dy = p / 5, dx = p % 5;
      uint2 d = *(const uint2*)(xl0 + (dy * 67 + dx) * 68);
      f16x2 x01, x23;
      *(uint_*)&x01 = d.x;
      *(uint_*)&x23 = d.y;
      float sp = fdot2h(x23, u23, fdot2h(x01, u01, 0.f));
      sp = dpp_add<0x121>(sp);
      sp = dpp_add<0x122>(sp);
      sp = dpp_add<0x124>(sp);
      sp = dpp_add<0x128>(sp);
      float e = __expf(sp);
      Z += e;
      f16x2 c0 = cvt_pk2h(e * wpos[p], e * wpos[p]);
      f16x2 c1 = cvt_pk2h(e * wpos[32 + p], e * wpos[32 + p]);
      g0a = x01 * c0 + g0a;
      g0b = x23 * c0 + g0b;
      g1a = x01 * c1 + g1a;
      g1b = x23 * c1 + g1b;
    }
    float rZ = 256.f / Z;
    f16x2 rZpk = cvt_pk2h(rZ, rZ);

    uint2 w0, w1;
    w0.x = h2u(g0a * rZpk); w0.y = h2u(g0b * rZpk);
    w1.x = h2u(g1a * rZpk); w1.y = h2u(g1b * rZpk);
    *(uint2*)&GU.Gl[r][lr * 4] = w0;
    *(uint2*)&GU.Gl[r][64 + lr * 4] = w1;
  }

  __syncthreads();

  {
    f4 acc0 = (f4)0.f, acc1 = (f4)0.f;
    #pragma unroll
    for (int ks = 0; ks < 4; ++ks) {
      f16x8 b0 = *reinterpret_cast<const f16x8*>(&GU.Gl[lr][ks * 32 + q * 8]);
      f16x8 b1 = *reinterpret_cast<const f16x8*>(&GU.Gl[16 + lr][ks * 32 + q * 8]);
      f16x8 ah = *reinterpret_cast<const f16x8*>(
          WF + ((ks * 8 + wave) * 64 + lane) * 8);
      acc0 = __builtin_amdgcn_mfma_f32_16x16x32_f16(ah, b0, acc0, 0, 0, 0);
      acc1 = __builtin_amdgcn_mfma_f32_16x16x32_f16(ah, b1, acc1, 0, 0, 0);
    }
    int bb = pos0 >> 12;
    int hw0 = pos0 & 4095;
    float* op = out + (size_t)bb * (OC_ * HO_ * WO_) + hw0;
    #pragma unroll
    for (int rr = 0; rr < 4; ++rr) {
      int c = wave * 16 + q * 4 + rr;
      op[(size_t)c * 4096 + lr] = acc0[rr];
      op[(size_t)c * 4096 + 16 + lr] = acc1[rr];
    }
  }
}

// ---------------------------------------------------------------------------
// PROBE 0 (diagnostic): staging + U-MFMA + barrier, x16 reps. Idempotent,
// writes only to dummy ws. Surfaces warm staging/barrier cost in top-5.
// ---------------------------------------------------------------------------
__global__ __launch_bounds__(512) void probe0_kernel(
    const u16* __restrict__ xbt, const u16* __restrict__ MF,
    float* __restrict__ dummy) {
  __shared__ u16 Xl[5 * 67 * 68];
  __shared__ union { float Ul[32][68]; u16 Gl[32][136]; } GU;

  int tid = threadIdx.x;
  int wave = tid >> 6, lane = tid & 63;
  int lr = lane & 15, q = lane >> 4;
  int bid = (int)blockIdx.x;
  int swz = (bid & 7) * 128 + (bid >> 3);
  int pos0 = swz * 32;
  int b = pos0 >> 12;
  int ho0 = (pos0 >> 6) & 63;
  int y0 = 2 * ho0, x0base = 2 * (pos0 & 63);

  float keep = 0.f;
  #pragma unroll 1
  for (int rep = 0; rep < 16; ++rep) {
    {
      int sl = tid & 15;
      int pi0 = tid >> 4;
      const u16* xbb = xbt + (size_t)b * (H_ * W_ * 64);
      #pragma unroll
      for (int it = 0; it < 11; ++it) {
        int pi = it * 32 + pi0;
        if (pi < 335) {
          int row = pi / 67;
          int col = pi - row * 67;
          int yr = y0 + row - 2, xr = x0base + col - 2;
          bool oob = ((unsigned)yr >= (unsigned)H_) | ((unsigned)xr >= (unsigned)W_);
          int yc = min(max(yr, 0), H_ - 1);
          int xc = min(max(xr, 0), W_ - 1);
          uint2 d = *(const uint2*)(xbb + ((size_t)yc * W_ + xc) * 64 + sl * 4);
          if (oob) { d.x = 0u; d.y = 0u; }
          *(uint2*)(&Xl[pi * 68 + sl * 4]) = d;
        }
      }
    }
    {
      int pt = wave >> 2, mm = wave & 3;
      int pu = pos0 + pt * 16 + lr;
      int bu = pu >> 12, hou = (pu >> 6) & 63, wou = pu & 63;
      const u16* xq = xbt + ((size_t)(bu * H_ + 2 * hou) * W_ + 2 * wou) * 64;
      f4 ua = (f4)0.f;
      #pragma unroll
      for (int ks = 0; ks < 2; ++ks) {
        f16x8 bb = *reinterpret_cast<const f16x8*>(xq + ks * 32 + q * 8);
        f16x8 ah = *reinterpret_cast<const f16x8*>(
            MF + ((ks * 4 + mm) * 64 + lane) * 8);
        ua = __builtin_amdgcn_mfma_f32_16x16x32_f16(ah, bb, ua, 0, 0, 0);
      }
      #pragma unroll
      for (int r = 0; r < 4; ++r)
        GU.Ul[pt * 16 + lr][mm * 16 + q * 4 + r] = ua[r];
    }
    __syncthreads();
    keep += GU.Ul[(tid >> 4) & 31][tid & 63] + (float)*(const f16*)&Xl[tid];
    __syncthreads();
  }
  dummy[(size_t)bid * 512 + tid] = keep;
}

// ---------------------------------------------------------------------------
// PROBE 1 (diagnostic): the exact phase-1 tap loop x16 on self-initialized
// LDS. Idempotent, writes only to dummy. Surfaces pure phase-1 cost.
// ---------------------------------------------------------------------------
__global__ __launch_bounds__(512) void probe1_kernel(
    const float* __restrict__ wpos, float* __restrict__ dummy) {
  __shared__ u16 Xl[5 * 67 * 68];
  __shared__ union { float Ul[32][68]; u16 Gl[32][136]; } GU;

  int tid = threadIdx.x;
  int wave = tid >> 6, lane = tid & 63;
  int lr = lane & 15, q = lane >> 4;

  // deterministic LDS init
  for (int i = tid; i < 5 * 67 * 34; i += 512)
    ((uint_*)Xl)[i] = 0x2C012C01u + (uint_)(i & 3);
  for (int i = tid; i < 32 * 68; i += 512)
    (&GU.Ul[0][0])[i] = 0.03f + (float)(i & 7) * 0.001f;
  __syncthreads();

  float keep = 0.f;
  #pragma unroll 1
  for (int rep = 0; rep < 16; ++rep) {
    int r = wave * 4 + q;
    const u16* xl0 = &Xl[(2 * r) * 68 + lr * 4];

    f4 u = *reinterpret_cast<const f4*>(&GU.Ul[r][lr * 4]);
    f16x2 u01 = cvt_pk2h(u.x, u.y);
    f16x2 u23 = cvt_pk2h(u.z, u.w);

    float Z = 0.f;
    f16x2 g0a = (f16x2)0.f, g0b = (f16x2)0.f;
    f16x2 g1a = (f16x2)0.f, g1b = (f16x2)0.f;

    #pragma unroll
    for (int p = 0; p < 25; ++p) {
      const int dy = p / 5, dx = p % 5;
      uint2 d = *(const uint2*)(xl0 + (dy * 67 + dx) * 68);
      f16x2 x01, x23;
      *(uint_*)&x01 = d.x;
      *(uint_*)&x23 = d.y;
      float sp = fdot2h(x23, u23, fdot2h(x01, u01, 0.f));
      sp = dpp_add<0x121>(sp);
      sp = dpp_add<0x122>(sp);
      sp = dpp_add<0x124>(sp);
      sp = dpp_add<0x128>(sp);
      float e = __expf(sp);
      Z += e;
      f16x2 c0 = cvt_pk2h(e * wpos[p], e * wpos[p]);
      f16x2 c1 = cvt_pk2h(e * wpos[32 + p], e * wpos[32 + p]);
      g0a = x01 * c0 + g0a;
      g0b = x23 * c0 + g0b;
      g1a = x01 * c1 + g1a;
      g1b = x23 * c1 + g1b;
    }
    float rZ = 256.f / Z;
    f16x2 rZpk = cvt_pk2h(rZ, rZ);

    uint2 w0, w1;
    w0.x = h2u(g0a * rZpk); w0.y = h2u(g0b * rZpk);
    w1.x = h2u(g1a * rZpk); w1.y = h2u(g1b * rZpk);
    *(uint2*)&GU.Gl[r][lr * 4] = w0;
    *(uint2*)&GU.Gl[r][64 + lr * 4] = w1;
    __syncthreads();
    keep += (float)*(const f16*)&GU.Gl[tid & 31][(tid * 7) & 127];
    __syncthreads();
  }
  dummy[(size_t)524288 + (size_t)blockIdx.x * 512 + tid] = keep;
}

// ---------------------------------------------------------------------------
extern "C" void kernel_launch(void* const* d_in, const int* in_sizes, int n_in,
                              void* d_out, int out_size, void* d_ws, size_t ws_size,
                              hipStream_t stream) {
  const float* x       = (const float*)d_in[0];
  const float* w_q     = (const float*)d_in[1];
  const float* w_k     = (const float*)d_in[2];
  const float* w_v     = (const float*)d_in[3];
  const float* row_emb = (const float*)d_in[4];
  const float* col_emb = (const float*)d_in[5];
  const float* mix_emb = (const float*)d_in[6];
  float* out = (float*)d_out;

  float* ws   = (float*)d_ws;
  u16*   xbt  = (u16*)(ws + XBT_OFF);
  u16*   MF   = (u16*)(ws + MF_OFF);
  u16*   WF   = (u16*)(ws + WF_OFF);
  float* wpos = ws + WPOS_OFF;
  float* dummy = ws + DUMMY_OFF;

  mega_kernel<<<1024 + 33, 256, 0, stream>>>(x, xbt, w_q, w_k, w_v, row_emb,
                                             col_emb, mix_emb, MF, WF, wpos);
  attn_out_kernel<<<NPOS / 32, 512, 0, stream>>>(xbt, MF, wpos, WF, out);
  probe0_kernel<<<1024, 512, 0, stream>>>(xbt, MF, dummy);
  probe1_kernel<<<1024, 512, 0, stream>>>(wpos, dummy);
}

// Round 13
// 35.066 us; speedup vs baseline: 5.2321x; 5.2321x over previous
//
#include <hip/hip_runtime.h>

typedef unsigned int   uint_;
typedef unsigned short u16;
typedef _Float16 f16;
typedef __attribute__((ext_vector_type(8))) _Float16 f16x8;  // MFMA A/B frag
typedef __attribute__((ext_vector_type(2))) __fp16 h2;       // builtin half2
typedef __attribute__((ext_vector_type(4))) float f4;

// Problem constants
#define B_    8
#define CIN_  64
#define H_    128
#define W_    128
#define OC_   128
#define HO_   64
#define WO_   64
#define NPOS  (B_ * HO_ * WO_)   // 32768

// ws layout (float offsets)
#define XBT_OFF  0          // f16 x_bt (B,H,W,64) = 4194304 floats
#define MF_OFF   4194304    // u16[4096]  (f16 M frags, pre-scaled by log2e)
#define WF_OFF   4196352    // u16[16384] (f16 Wv frags)
#define WPOS_OFF 4204544    // wpos0[25] @ +0, wpos1[25] @ +32 (plain softmax)

// ---------------------------------------------------------------------------
// helpers (all register bitcasts, no unions)
// ---------------------------------------------------------------------------
__device__ __forceinline__ u16 f2h_bits(float x) {
  return __builtin_bit_cast(u16, (f16)x);
}
__device__ __forceinline__ uint_ cvt_pk_u(float lo, float hi) {
  return __builtin_bit_cast(uint_, __builtin_amdgcn_cvt_pkrtz(lo, hi));
}
__device__ __forceinline__ float fdot2u(uint_ a, uint_ b, float c) {
  return __builtin_amdgcn_fdot2(__builtin_bit_cast(h2, a),
                                __builtin_bit_cast(h2, b), c, false);
}
template <int CTRL>
__device__ __forceinline__ float dpp_add(float x) {
  int y = __builtin_amdgcn_update_dpp(0, __float_as_int(x), CTRL, 0xf, 0xf, true);
  return x + __int_as_float(y);
}
// guaranteed single-instruction packed f16 ops
__device__ __forceinline__ void pk_fma(uint_& acc, uint_ x, uint_ c) {
  asm("v_pk_fma_f16 %0, %1, %2, %0" : "+v"(acc) : "v"(x), "v"(c));
}
__device__ __forceinline__ uint_ pk_mul(uint_ a, uint_ b) {
  uint_ r;
  asm("v_pk_mul_f16 %0, %1, %2" : "=v"(r) : "v"(a), "v"(b));
  return r;
}

// ---------------------------------------------------------------------------
// Dispatch 1 (mega): blocks 0..1023 = transpose x f32 -> xbt f16;
// blocks 1024..1056 = prep (M frags f16 * log2e, wpos, Wv frags f16).
// A-frag layout (16x16x32): lane=(i&15)+16*((k>>3)&3), reg=k&7.
// ---------------------------------------------------------------------------
__global__ __launch_bounds__(256) void mega_kernel(
    const float* __restrict__ x, u16* __restrict__ xbt,
    const float* __restrict__ w_q, const float* __restrict__ w_k,
    const float* __restrict__ w_v,
    const float* __restrict__ row_emb, const float* __restrict__ col_emb,
    const float* __restrict__ mix_emb,
    u16* __restrict__ MF, u16* __restrict__ WF, float* __restrict__ wpos) {
  if (blockIdx.x < 1024) {
    __shared__ float tile[64][129];
    int by = blockIdx.x;
    int b = by >> 7, y = by & 127;
    const float* xp = x + (size_t)b * (CIN_ * H_ * W_) + (size_t)y * W_;
    #pragma unroll
    for (int it = 0; it < 32; ++it) {
      int idx = threadIdx.x + it * 256;
      int c = idx >> 7, xw = idx & 127;
      tile[c][xw] = xp[(size_t)c * (H_ * W_) + xw];
    }
    __syncthreads();
    uint_* dst = (uint_*)(xbt + ((size_t)(b * H_ + y)) * (W_ * 64));
    #pragma unroll
    for (int it = 0; it < 16; ++it) {
      int idx = threadIdx.x + it * 256;   // = xw*32 + cp
      int xw = idx >> 5, cp = idx & 31;
      dst[idx] = cvt_pk_u(tile[2 * cp][xw], tile[2 * cp + 1][xw]);
    }
  } else {
    int pb = blockIdx.x - 1024;   // 0..32
    if (pb < 16) {
      // M[a][c] = sum_o w_q[o,a] * w_k[o,c], scaled by log2(e) for exp2 path
      int idx = pb * 256 + threadIdx.x;  // 0..4095
      int a = idx >> 6, c = idx & 63;
      float acc = 0.f;
      #pragma unroll 8
      for (int o = 0; o < 128; ++o)
        acc = fmaf(w_q[o * 64 + a], w_k[o * 64 + c], acc);
      int m = c >> 4, lr = c & 15;
      int ks = a >> 5, q = (a >> 3) & 3, jr = a & 7;
      int off = ((ks * 4 + m) * 64 + (lr + 16 * q)) * 8 + jr;
      MF[off] = f2h_bits(acc * 1.44269504f);
    } else if (pb == 16) {
      int p = threadIdx.x;
      if (p < 25) {
        int i = p / 5, j = p % 5;
        float a0 = 0.f, a1 = 0.f;
        for (int c = 0; c < 128; ++c) {
          float rc = row_emb[c * 5 + i] + col_emb[c * 5 + j];
          a0 = fmaf(rc, mix_emb[c * 2 + 0], a0);
          a1 = fmaf(rc, mix_emb[c * 2 + 1], a1);
        }
        float mx = fmaxf(a0, a1);
        float e0 = __expf(a0 - mx), e1 = __expf(a1 - mx);
        float inv = 1.f / (e0 + e1);
        wpos[p] = e0 * inv;
        wpos[32 + p] = e1 * inv;
      }
    } else {
      // Wv[c][k] = w_v[c*128+k]; A-frag (i=c, k), 8 m-tiles (c=128)
      int t = (pb - 17) * 256 + threadIdx.x;  // 0..4095
      #pragma unroll
      for (int e = 0; e < 4; ++e) {
        int elem = t * 4 + e;            // = c*128 + k
        int c = elem >> 7, k = elem & 127;
        int m = c >> 4, lr = c & 15;
        int ks = k >> 5, q = (k >> 3) & 3, j = k & 7;
        int off = ((ks * 8 + m) * 64 + (lr + 16 * q)) * 8 + j;
        WF[off] = f2h_bits(w_v[elem]);
      }
    }
  }
}

// ---------------------------------------------------------------------------
// Dispatch 2 (fused stage + U + attn + out GEMM). 512 thr (8 waves) = 32 pos.
// Phase 1 per tap (guaranteed codegen): 1 ds_read_b64 + 2 v_dot2_f32_f16 +
// 4 v_add_f32(dpp) + 1 v_sub + 1 v_exp + 1 v_add + 2 v_mul + 2 v_cvt_pkrtz +
// 4 v_pk_fma_f16(asm).  e = exp2(sp-8): 2^-8 pre-scale is softmax-invariant
// and keeps everything in f16 range.
// LDS: Xl [5][67][64] u16 = 41.9K + union-free Ul/Gl overlay 8.5K -> 3 blk/CU.
// grid = NPOS/32 = 1024, XCD-swizzled.
// ---------------------------------------------------------------------------
__global__ __launch_bounds__(512) void attn_out_kernel(
    const u16* __restrict__ xbt, const u16* __restrict__ MF,
    const float* __restrict__ wpos, const u16* __restrict__ WF,
    float* __restrict__ out) {
  __shared__ u16 Xl[5 * 67 * 64];   // [row][col][ch], ch-stride 64 u16 = 128 B
  __shared__ union {
    float Ul[32][68];               // row stride 272 B
    u16   Gl[32][136];
  } GU;

  int tid = threadIdx.x;
  int wave = tid >> 6, lane = tid & 63;
  int lr = lane & 15, q = lane >> 4;

  int bid = (int)blockIdx.x;
  int swz = (bid & 7) * 128 + (bid >> 3);   // XCD owns one batch image
  int pos0 = swz * 32;

  int b = pos0 >> 12;
  int ho0 = (pos0 >> 6) & 63;
  int y0 = 2 * ho0, x0base = 2 * (pos0 & 63);

  // ----- Stage x-window -> Xl, ZERO for OOB (handles all padding) -----
  {
    int sl = tid & 15;
    int pi0 = tid >> 4;
    const u16* xbb = xbt + (size_t)b * (H_ * W_ * 64);
    #pragma unroll
    for (int it = 0; it < 11; ++it) {
      int pi = it * 32 + pi0;       // 0..351, need 0..334
      if (pi < 335) {
        int row = pi / 67;
        int col = pi - row * 67;
        int yr = y0 + row - 2, xr = x0base + col - 2;
        bool oob = ((unsigned)yr >= (unsigned)H_) | ((unsigned)xr >= (unsigned)W_);
        int yc = min(max(yr, 0), H_ - 1);
        int xc = min(max(xr, 0), W_ - 1);
        uint2 d = *(const uint2*)(xbb + ((size_t)yc * W_ + xc) * 64 + sl * 4);
        if (oob) { d.x = 0u; d.y = 0u; }
        *(uint2*)(&Xl[pi * 64 + sl * 4]) = d;
      }
    }
  }

  // ----- Phase 0: U = M^T xq (f16 M * log2e) -----
  {
    int pt = wave >> 2, mm = wave & 3;      // pos-tile (0,1), m-tile (0..3)
    int pu = pos0 + pt * 16 + lr;
    int bu = pu >> 12, hou = (pu >> 6) & 63, wou = pu & 63;
    const u16* xq = xbt + ((size_t)(bu * H_ + 2 * hou) * W_ + 2 * wou) * 64;
    f4 ua = (f4)0.f;
    #pragma unroll
    for (int ks = 0; ks < 2; ++ks) {
      f16x8 bb = *reinterpret_cast<const f16x8*>(xq + ks * 32 + q * 8);
      f16x8 ah = *reinterpret_cast<const f16x8*>(
          MF + ((ks * 4 + mm) * 64 + lane) * 8);
      ua = __builtin_amdgcn_mfma_f32_16x16x32_f16(ah, bb, ua, 0, 0, 0);
    }
    #pragma unroll
    for (int r = 0; r < 4; ++r)
      GU.Ul[pt * 16 + lr][mm * 16 + q * 4 + r] = ua[r];
  }
  __syncthreads();

  // ----- Phase 1: attention, lean 25-tap loop -----
  {
    int r = wave * 4 + q;              // local position 0..31
    const u16* xl0 = &Xl[(2 * r) * 64 + lr * 4];

    f4 u = *reinterpret_cast<const f4*>(&GU.Ul[r][lr * 4]);
    uint_ u01 = cvt_pk_u(u.x, u.y);
    uint_ u23 = cvt_pk_u(u.z, u.w);

    float Z = 0.f;
    uint_ g0a = 0u, g0b = 0u, g1a = 0u, g1b = 0u;   // packed f16 (+0,+0)

    #pragma unroll
    for (int p = 0; p < 25; ++p) {
      const int dy = p / 5, dx = p % 5;
      uint2 d = *(const uint2*)(xl0 + (dy * 67 + dx) * 64);
      float sp = fdot2u(d.y, u23, fdot2u(d.x, u01, 0.f));
      sp = dpp_add<0x121>(sp);   // row_ror:1
      sp = dpp_add<0x122>(sp);   // row_ror:2
      sp = dpp_add<0x124>(sp);   // row_ror:4
      sp = dpp_add<0x128>(sp);   // row_ror:8 -> full 64-ch sum per row
      float e = __builtin_amdgcn_exp2f(sp - 8.f);  // 2^-8 softmax-invariant
      Z += e;
      uint_ c0 = cvt_pk_u(e * wpos[p], e * wpos[p]);
      uint_ c1 = cvt_pk_u(e * wpos[32 + p], e * wpos[32 + p]);
      pk_fma(g0a, d.x, c0);
      pk_fma(g0b, d.y, c0);
      pk_fma(g1a, d.x, c1);
      pk_fma(g1b, d.y, c1);
    }
    float rZ = 1.f / Z;
    uint_ rZpk = cvt_pk_u(rZ, rZ);

    uint2 w0, w1;
    w0.x = pk_mul(g0a, rZpk); w0.y = pk_mul(g0b, rZpk);
    w1.x = pk_mul(g1a, rZpk); w1.y = pk_mul(g1b, rZpk);
    *(uint2*)&GU.Gl[r][lr * 4] = w0;
    *(uint2*)&GU.Gl[r][64 + lr * 4] = w1;
  }

  __syncthreads();

  // ----- Phase 2: out GEMM (f16 Wv frags) -----
  {
    f4 acc0 = (f4)0.f, acc1 = (f4)0.f;
    #pragma unroll
    for (int ks = 0; ks < 4; ++ks) {
      f16x8 b0 = *reinterpret_cast<const f16x8*>(&GU.Gl[lr][ks * 32 + q * 8]);
      f16x8 b1 = *reinterpret_cast<const f16x8*>(&GU.Gl[16 + lr][ks * 32 + q * 8]);
      f16x8 ah = *reinterpret_cast<const f16x8*>(
          WF + ((ks * 8 + wave) * 64 + lane) * 8);
      acc0 = __builtin_amdgcn_mfma_f32_16x16x32_f16(ah, b0, acc0, 0, 0, 0);
      acc1 = __builtin_amdgcn_mfma_f32_16x16x32_f16(ah, b1, acc1, 0, 0, 0);
    }
    int bb = pos0 >> 12;
    int hw0 = pos0 & 4095;
    float* op = out + (size_t)bb * (OC_ * HO_ * WO_) + hw0;
    #pragma unroll
    for (int rr = 0; rr < 4; ++rr) {
      int c = wave * 16 + q * 4 + rr;
      op[(size_t)c * 4096 + lr] = acc0[rr];
      op[(size_t)c * 4096 + 16 + lr] = acc1[rr];
    }
  }
}

// ---------------------------------------------------------------------------
extern "C" void kernel_launch(void* const* d_in, const int* in_sizes, int n_in,
                              void* d_out, int out_size, void* d_ws, size_t ws_size,
                              hipStream_t stream) {
  const float* x       = (const float*)d_in[0];
  const float* w_q     = (const float*)d_in[1];
  const float* w_k     = (const float*)d_in[2];
  const float* w_v     = (const float*)d_in[3];
  const float* row_emb = (const float*)d_in[4];
  const float* col_emb = (const float*)d_in[5];
  const float* mix_emb = (const float*)d_in[6];
  float* out = (float*)d_out;

  float* ws   = (float*)d_ws;
  u16*   xbt  = (u16*)(ws + XBT_OFF);
  u16*   MF   = (u16*)(ws + MF_OFF);
  u16*   WF   = (u16*)(ws + WF_OFF);
  float* wpos = ws + WPOS_OFF;

  mega_kernel<<<1024 + 33, 256, 0, stream>>>(x, xbt, w_q, w_k, w_v, row_emb,
                                             col_emb, mix_emb, MF, WF, wpos);
  attn_out_kernel<<<NPOS / 32, 512, 0, stream>>>(xbt, MF, wpos, WF, out);
}